// Round 9
// baseline (290.319 us; speedup 1.0000x reference)
//
#include <hip/hip_runtime.h>

#define HID 512
#define NH 8
#define HD 64
#define BATCH 4
#define SEQ 2048
#define MTOT (BATCH * SEQ)   // 8192

typedef unsigned short ushort_t;
typedef __bf16 bf16x8 __attribute__((ext_vector_type(8)));
typedef unsigned short ushort8v __attribute__((ext_vector_type(8)));
typedef unsigned short ushort4v __attribute__((ext_vector_type(4)));
typedef float floatx4 __attribute__((ext_vector_type(4)));
typedef unsigned int uintx4 __attribute__((ext_vector_type(4)));

static __device__ __forceinline__ unsigned short f2bf(float f) {
  __bf16 b = (__bf16)f;                    // hw v_cvt_pk_bf16_f32 (RNE)
  return __builtin_bit_cast(unsigned short, b);
}
static __device__ __forceinline__ float bf2f(unsigned short s) {
  union { unsigned int u; float f; } c; c.u = ((unsigned int)s) << 16;
  return c.f;
}
static __device__ __forceinline__ bf16x8 asbf(ushort8v v) {
  return __builtin_bit_cast(bf16x8, v);
}
static __device__ __forceinline__ float max3f(float a, float b, float c) {
  return fmaxf(fmaxf(a, b), c);            // v_max3_f32
}
static __device__ __forceinline__ float fexp2(float x) {
  return __builtin_amdgcn_exp2f(x);        // raw v_exp_f32
}
// async global->LDS, 16B/lane, linear dest (wave-uniform base + lane*16)
static __device__ __forceinline__ void gl_lds16(const ushort_t* g, ushort_t* l) {
  __builtin_amdgcn_global_load_lds(
      (const __attribute__((address_space(1))) void*)g,
      (__attribute__((address_space(3))) void*)l, 16, 0, 0);
}

// ---------- inline dtype detection (proven round 8) ----------
static __device__ __forceinline__ int detect_bf(const unsigned int* __restrict__ q) {
  int lane = threadIdx.x & 63;
  int hits = 0;
#pragma unroll
  for (int i = 0; i < 4; ++i) {
    unsigned e = (q[lane * 4 + i] >> 7) & 0xff;
    hits += (e >= 110 && e <= 136) ? 1 : 0;
  }
#pragma unroll
  for (int s = 1; s < 64; s <<= 1) hits += __shfl_xor(hits, s);
  return hits >= 128 ? 1 : 0;
}

// 0.125 (1/sqrt(64)) * log2(e): softmax in exp2 domain.
#define SC_LOG2E 0.18033688011112042f

// ---------- fused prep (proven round 8 verbatim) ----------
__global__ __launch_bounds__(256) void prep_all(
    const void* __restrict__ W0, const void* __restrict__ W1,
    const void* __restrict__ W2, const void* __restrict__ W3,
    ushort_t* __restrict__ T0, ushort_t* __restrict__ T1,
    ushort_t* __restrict__ T2, ushort_t* __restrict__ T3,
    const void* __restrict__ B0, const void* __restrict__ B1,
    const void* __restrict__ B2, const void* __restrict__ B3,
    float* __restrict__ biasF, const int* __restrict__ mask,
    float* __restrict__ mb, const unsigned int* __restrict__ qd) {
  const int bx = blockIdx.x;
  const int isbf = detect_bf(qd);
  if (bx < 256) {
    const int sel = bx >> 6, t = bx & 63;
    const void* W; ushort_t* T;
    switch (sel) {
      case 0: W = W0; T = T0; break;
      case 1: W = W1; T = T1; break;
      case 2: W = W2; T = T2; break;
      default: W = W3; T = T3; break;
    }
    __shared__ ushort_t Ts[64 * 72];
    const int tid = threadIdx.x;
    const int kt = (t >> 3) * 64;
    const int nt = (t & 7) * 64;
    const int r = tid >> 2;             // 0..63
    const int c = (tid & 3) * 16;       // 0,16,32,48

    ushort8v v0, v1;
    if (isbf) {
      const ushort_t* p = (const ushort_t*)W + (long)(kt + r) * HID + nt + c;
      v0 = *(const ushort8v*)(p);
      v1 = *(const ushort8v*)(p + 8);
    } else {
      const float* p = (const float*)W + (long)(kt + r) * HID + nt + c;
      floatx4 f0 = *(const floatx4*)(p);
      floatx4 f1 = *(const floatx4*)(p + 4);
      floatx4 f2 = *(const floatx4*)(p + 8);
      floatx4 f3 = *(const floatx4*)(p + 12);
#pragma unroll
      for (int i = 0; i < 4; ++i) {
        v0[i] = f2bf(f0[i]); v0[4 + i] = f2bf(f1[i]);
        v1[i] = f2bf(f2[i]); v1[4 + i] = f2bf(f3[i]);
      }
    }
    *(ushort8v*)(&Ts[r * 72 + c])     = v0;
    *(ushort8v*)(&Ts[r * 72 + c + 8]) = v1;
    __syncthreads();
    ushort8v o0, o1;
#pragma unroll
    for (int j = 0; j < 8; ++j) o0[j] = Ts[(c + j) * 72 + r];
#pragma unroll
    for (int j = 0; j < 8; ++j) o1[j] = Ts[(c + 8 + j) * 72 + r];
    ushort_t* q = T + (long)(nt + r) * HID + kt + c;
    *(ushort8v*)(q)     = o0;
    *(ushort8v*)(q + 8) = o1;
  } else if (bx < 264) {
    int i = (bx - 256) * 256 + threadIdx.x;
    int t = i >> 9, j = i & 511;
    const void* B = (t == 0) ? B0 : (t == 1) ? B1 : (t == 2) ? B2 : B3;
    biasF[i] = isbf ? bf2f(((const ushort_t*)B)[j]) : ((const float*)B)[j];
  } else {
    int i = (bx - 264) * 256 + threadIdx.x;
    mb[i] = mask[i] ? 0.f : -1e9f;
  }
}

// ---------- QKV GEMM v3 (proven round 8 verbatim) ----------
__global__ __launch_bounds__(256) void gemm_qkv3(
    const void* __restrict__ X0, const void* __restrict__ X1, const void* __restrict__ X2,
    const ushort_t* __restrict__ WtBase, const float* __restrict__ biasBase,
    ushort_t* __restrict__ YBase) {
  const int isbf = detect_bf((const unsigned int*)X0);
  int lin = blockIdx.x + 256 * blockIdx.z;          // 0..767
  int swz = (lin & 7) * 96 + (lin >> 3);            // bijective: 768 = 8*96
  const int z = swz >> 8;                           // 0..2
  const int mblk = swz & 255;                       // 0..255
  const void* X = (z == 0) ? X0 : (z == 1) ? X1 : X2;
  const ushort_t* Wt = WtBase + (size_t)z * HID * HID;
  const float* biasF = biasBase + (size_t)z * HID;
  ushort_t* Y = YBase + (size_t)z * MTOT * HID;

  const int tid = threadIdx.x;
  const int wid = tid >> 6, lane = tid & 63;
  const int id = lane & 15, quad = lane >> 4;
  const int m0 = mblk * 32;

  __shared__ ushort_t As[32 * 32];     // 2KB
  __shared__ ushort_t Bs[512 * 32];    // 32KB

  const int a_r = tid >> 3;
  const int a_o = (tid & 1) * 4;
  const int a_pb = ((tid & 7) >> 1) ^ (a_r & 3);
  const int b_ro = lane >> 2;
  const int b_scb = (lane & 3);

  floatx4 acc[2][8];
#pragma unroll
  for (int i = 0; i < 2; ++i)
#pragma unroll
    for (int j = 0; j < 8; ++j) acc[i][j] = (floatx4){0.f, 0.f, 0.f, 0.f};

  for (int k0 = 0; k0 < HID; k0 += 32) {
    ushort4v aW;
    if (isbf) {
      aW = *(const ushort4v*)((const ushort_t*)X + (long)(m0 + a_r) * HID + k0 + (tid & 7) * 4);
    } else {
      floatx4 f = *(const floatx4*)((const float*)X + (long)(m0 + a_r) * HID + k0 + (tid & 7) * 4);
#pragma unroll
      for (int i = 0; i < 4; ++i) aW[i] = f2bf(f[i]);
    }
    __syncthreads();
    *(ushort4v*)(&As[a_r * 32 + (a_pb << 3) + a_o]) = aW;
#pragma unroll
    for (int i = 0; i < 8; ++i) {
      int rb = wid * 128 + i * 16;
      int srow = rb + b_ro;
      gl_lds16(Wt + (long)srow * HID + k0 + ((b_scb ^ (srow & 3)) << 3), &Bs[rb * 32]);
    }
    __syncthreads();
    {
      ushort8v af[2], bfv[8];
      const int pb = (quad ^ (id & 3)) << 3;
#pragma unroll
      for (int ms = 0; ms < 2; ++ms)
        af[ms] = *(const ushort8v*)(&As[(ms * 16 + id) * 32 + pb]);
#pragma unroll
      for (int ns = 0; ns < 8; ++ns)
        bfv[ns] = *(const ushort8v*)(&Bs[(wid * 128 + ns * 16 + id) * 32 + pb]);
#pragma unroll
      for (int ms = 0; ms < 2; ++ms)
#pragma unroll
        for (int ns = 0; ns < 8; ++ns)
          acc[ms][ns] = __builtin_amdgcn_mfma_f32_16x16x32_bf16(asbf(af[ms]), asbf(bfv[ns]), acc[ms][ns], 0, 0, 0);
    }
  }
#pragma unroll
  for (int ns = 0; ns < 8; ++ns) {
    int col = wid * 128 + ns * 16 + id;
    float bv = biasF[col];
#pragma unroll
    for (int ms = 0; ms < 2; ++ms) {
      int row0 = m0 + ms * 16 + quad * 4;
#pragma unroll
      for (int r = 0; r < 4; ++r)
        Y[(long)(row0 + r) * HID + col] = f2bf(acc[ms][ns][r] + bv);
    }
  }
}

// ---------- out-proj GEMM (proven round 8 verbatim) ----------
__global__ __launch_bounds__(256) void gemm_out2(
    const ushort_t* __restrict__ X, const ushort_t* __restrict__ Wt,
    const float* __restrict__ biasF, void* __restrict__ out,
    const unsigned int* __restrict__ qd) {
  const int isbf = detect_bf(qd);
  const int tid = threadIdx.x;
  const int wid = tid >> 6, lane = tid & 63;
  const int id = lane & 15, quad = lane >> 4;
  const int wm = wid >> 1, wn = wid & 1;
  const int m0 = blockIdx.x * 64, n0 = blockIdx.y * 128;

  __shared__ ushort_t As[64 * 64];
  __shared__ ushort_t Bs[128 * 64];

  const int lrow = lane >> 3;
  const int scb  = (lane & 7) ^ lrow;

  floatx4 acc[2][4];
#pragma unroll
  for (int i = 0; i < 2; ++i)
#pragma unroll
    for (int j = 0; j < 4; ++j) acc[i][j] = (floatx4){0.f, 0.f, 0.f, 0.f};

  for (int k0 = 0; k0 < HID; k0 += 64) {
    __syncthreads();
#pragma unroll
    for (int i = 0; i < 2; ++i) {
      int r = wid * 16 + i * 8 + lrow;
      gl_lds16(X + (long)(m0 + r) * HID + k0 + scb * 8, &As[(wid * 16 + i * 8) * 64]);
    }
#pragma unroll
    for (int i = 0; i < 4; ++i) {
      int r = wid * 32 + i * 8 + lrow;
      gl_lds16(Wt + (long)(n0 + r) * HID + k0 + scb * 8, &Bs[(wid * 32 + i * 8) * 64]);
    }
    __syncthreads();
#pragma unroll
    for (int kk = 0; kk < 64; kk += 32) {
      ushort8v af[2], bfv[4];
      const int cb = (kk >> 3) + quad;
#pragma unroll
      for (int ms = 0; ms < 2; ++ms) {
        int row = wm * 32 + ms * 16 + id;
        af[ms] = *(const ushort8v*)(&As[row * 64 + ((cb ^ (id & 7)) << 3)]);
      }
#pragma unroll
      for (int ns = 0; ns < 4; ++ns) {
        int row = wn * 64 + ns * 16 + id;
        bfv[ns] = *(const ushort8v*)(&Bs[row * 64 + ((cb ^ (id & 7)) << 3)]);
      }
#pragma unroll
      for (int ms = 0; ms < 2; ++ms)
#pragma unroll
        for (int ns = 0; ns < 4; ++ns)
          acc[ms][ns] = __builtin_amdgcn_mfma_f32_16x16x32_bf16(asbf(af[ms]), asbf(bfv[ns]), acc[ms][ns], 0, 0, 0);
    }
  }
#pragma unroll
  for (int ns = 0; ns < 4; ++ns) {
    int col = n0 + wn * 64 + ns * 16 + id;
    float bv = biasF[col];
#pragma unroll
    for (int ms = 0; ms < 2; ++ms) {
      int row0 = m0 + wm * 32 + ms * 16 + quad * 4;
      if (isbf) {
        ushort_t* o = (ushort_t*)out;
#pragma unroll
        for (int r = 0; r < 4; ++r) o[(long)(row0 + r) * HID + col] = f2bf(acc[ms][ns][r] + bv);
      } else {
        float* o = (float*)out;
#pragma unroll
        for (int r = 0; r < 4; ++r) o[(long)(row0 + r) * HID + col] = acc[ms][ns][r] + bv;
      }
    }
  }
}

// ---------- flash attention — ROUND-3 VERSION VERBATIM (proven ~79-81us) ----------
__global__ __launch_bounds__(512) void flash_attn(
    const ushort_t* __restrict__ Q, const ushort_t* __restrict__ K,
    const ushort_t* __restrict__ V, const float* __restrict__ mb,
    ushort_t* __restrict__ ctx) {
  int lin = blockIdx.x + 16 * blockIdx.y + 128 * blockIdx.z;   // 0..511
  int swz = (lin & 7) * 64 + (lin >> 3);                       // bijective
  const int qblk = swz & 15, h = (swz >> 4) & 7, b = swz >> 7;
  const int tid = threadIdx.x;
  const int wid = tid >> 6, lane = tid & 63;
  const int id = lane & 15, quad = lane >> 4;

  __shared__ ushort_t Kt[64 * 72];       // [key][d] stride 72
  __shared__ ushort_t Vt[64 * 72];       // [d][key] stride 72 (transposed)
  __shared__ ushort_t Pl[8][16 * 72];    // per-wave P as [q][key] stride 72

  const ushort_t* Qb = Q + (long)(b * SEQ + qblk * 128 + wid * 16) * HID + h * HD;
  const ushort_t* Kb = K + (long)(b * SEQ) * HID + h * HD;
  const ushort_t* Vb = V + (long)(b * SEQ) * HID + h * HD;
  const float* mrow = mb + b * SEQ;

  ushort8v qf[2];
#pragma unroll
  for (int kh = 0; kh < 2; ++kh)
    qf[kh] = *(const ushort8v*)(Qb + id * HID + kh * 32 + quad * 8);

  floatx4 o[4];
  float m_i = -1e30f, l_i = 0.f;
#pragma unroll
  for (int dg = 0; dg < 4; ++dg) o[dg] = (floatx4){0, 0, 0, 0};

  const bool kstager = (tid < 256);
  const int t2 = tid & 255;
  const int skey = t2 >> 2;              // K: rows 0..63
  const int sdc  = (t2 & 3) * 16;        // K: cols 0,16,32,48
  const int vkp  = (t2 & 31) * 2;        // V: key pair 0..62
  const int vdc  = (t2 >> 5) * 8;        // V: d col 0..56

  ushort8v r0, r1;
  if (kstager) {
    const ushort_t* kpp = Kb + (long)skey * HID + sdc;
    r0 = *(const ushort8v*)(kpp);
    r1 = *(const ushort8v*)(kpp + 8);
  } else {
    const ushort_t* vp0 = Vb + (long)vkp * HID + vdc;
    r0 = *(const ushort8v*)(vp0);
    r1 = *(const ushort8v*)(vp0 + HID);
  }

  for (int kb = 0; kb < SEQ / 64; ++kb) {
    if (kstager) {
      *(ushort8v*)(&Kt[skey * 72 + sdc])     = r0;
      *(ushort8v*)(&Kt[skey * 72 + sdc + 8]) = r1;
    } else {
      uintx4 a = __builtin_bit_cast(uintx4, r0);
      uintx4 bq = __builtin_bit_cast(uintx4, r1);
#pragma unroll
      for (int j = 0; j < 4; ++j) {
        unsigned int d0 = __builtin_amdgcn_perm(bq[j], a[j], 0x05040100u);
        unsigned int d1 = __builtin_amdgcn_perm(bq[j], a[j], 0x07060302u);
        *(unsigned int*)(&Vt[(vdc + 2 * j) * 72 + vkp])     = d0;
        *(unsigned int*)(&Vt[(vdc + 2 * j + 1) * 72 + vkp]) = d1;
      }
    }
    __syncthreads();

    if (kb + 1 < SEQ / 64) {
      if (kstager) {
        const ushort_t* kpp = Kb + (long)((kb + 1) * 64 + skey) * HID + sdc;
        r0 = *(const ushort8v*)(kpp);
        r1 = *(const ushort8v*)(kpp + 8);
      } else {
        const ushort_t* vp0 = Vb + (long)((kb + 1) * 64 + vkp) * HID + vdc;
        r0 = *(const ushort8v*)(vp0);
        r1 = *(const ushort8v*)(vp0 + HID);
      }
    }

    floatx4 st[4];
    __builtin_amdgcn_s_setprio(1);
#pragma unroll
    for (int ks = 0; ks < 4; ++ks) {
      ushort8v kf0 = *(const ushort8v*)(&Kt[(ks * 16 + id) * 72 + quad * 8]);
      ushort8v kf1 = *(const ushort8v*)(&Kt[(ks * 16 + id) * 72 + 32 + quad * 8]);
      floatx4 a = (floatx4){0, 0, 0, 0};
      a = __builtin_amdgcn_mfma_f32_16x16x32_bf16(asbf(kf0), asbf(qf[0]), a, 0, 0, 0);
      a = __builtin_amdgcn_mfma_f32_16x16x32_bf16(asbf(kf1), asbf(qf[1]), a, 0, 0, 0);
      st[ks] = a;
    }
    __builtin_amdgcn_s_setprio(0);
#pragma unroll
    for (int ks = 0; ks < 4; ++ks) {
      floatx4 mbv = *(const floatx4*)(mrow + kb * 64 + ks * 16 + quad * 4);
#pragma unroll
      for (int r = 0; r < 4; ++r)
        st[ks][r] = fmaf(st[ks][r], SC_LOG2E, mbv[r]);
    }
    {
      float t0 = max3f(st[0][0], st[0][1], st[0][2]);
      float t1 = max3f(st[0][3], st[1][0], st[1][1]);
      float t2m = max3f(st[1][2], st[1][3], st[2][0]);
      float t3 = max3f(st[2][1], st[2][2], st[2][3]);
      float t4 = max3f(st[3][0], st[3][1], st[3][2]);
      float mx = max3f(t0, t1, st[3][3]);
      float mz = max3f(t2m, t3, t4);
      mx = fmaxf(mx, mz);
      mx = fmaxf(mx, __shfl_xor(mx, 16));
      mx = fmaxf(mx, __shfl_xor(mx, 32));
      if (!__all(mx - m_i <= 8.f)) {
        float mnew = fmaxf(m_i, mx);
        float alpha = fexp2(m_i - mnew);
        m_i = mnew;
        l_i *= alpha;
#pragma unroll
        for (int dg = 0; dg < 4; ++dg) o[dg] *= alpha;
      }
      float mcur = m_i;
      floatx4 rsv = (floatx4){0.f, 0.f, 0.f, 0.f};
#pragma unroll
      for (int ks = 0; ks < 4; ++ks) {
        ushort4v pk;
#pragma unroll
        for (int r = 0; r < 4; ++r) {
          float p = fexp2(st[ks][r] - mcur);
          rsv[r] += p;
          pk[r] = f2bf(p);
        }
        *(ushort4v*)(&Pl[wid][id * 72 + ks * 16 + quad * 4]) = pk;
      }
      float rs = (rsv[0] + rsv[1]) + (rsv[2] + rsv[3]);
      rs += __shfl_xor(rs, 16);
      rs += __shfl_xor(rs, 32);
      l_i += rs;
    }

    __builtin_amdgcn_s_setprio(1);
#pragma unroll
    for (int kc = 0; kc < 2; ++kc) {
      ushort8v pf = *(const ushort8v*)(&Pl[wid][id * 72 + kc * 32 + quad * 8]);
#pragma unroll
      for (int dg = 0; dg < 4; ++dg) {
        ushort8v vf = *(const ushort8v*)(&Vt[(dg * 16 + id) * 72 + kc * 32 + quad * 8]);
        o[dg] = __builtin_amdgcn_mfma_f32_16x16x32_bf16(asbf(vf), asbf(pf), o[dg], 0, 0, 0);
      }
    }
    __builtin_amdgcn_s_setprio(0);
    __syncthreads();
  }

  {
    float inv = 1.0f / l_i;
    long qrow = (long)(b * SEQ + qblk * 128 + wid * 16 + id);
#pragma unroll
    for (int dg = 0; dg < 4; ++dg) {
      ushort4v pk;
#pragma unroll
      for (int r = 0; r < 4; ++r) pk[r] = f2bf(o[dg][r] * inv);
      *(ushort4v*)(&ctx[qrow * HID + h * HD + dg * 16 + quad * 4]) = pk;
    }
  }
}

extern "C" void kernel_launch(void* const* d_in, const int* in_sizes, int n_in,
                              void* d_out, int out_size, void* d_ws, size_t ws_size,
                              hipStream_t stream) {
  const void* values = d_in[0];
  const void* keys   = d_in[1];
  const void* query  = d_in[2];
  const int*  mask   = (const int*)d_in[3];
  const void* Wq = d_in[4];  const void* bq = d_in[5];
  const void* Wk = d_in[6];  const void* bk = d_in[7];
  const void* Wv = d_in[8];  const void* bv = d_in[9];
  const void* Wo = d_in[10]; const void* bo = d_in[11];

  ushort_t* ws = (ushort_t*)d_ws;
  const size_t NEL = (size_t)MTOT * HID;
  ushort_t* Qp  = ws;                       // Qp/Kp/Vp contiguous
  ushort_t* Kp  = ws + NEL;
  ushort_t* Vp  = ws + 2 * NEL;
  ushort_t* Cp  = ws + 3 * NEL;
  ushort_t* WqT = ws + 4 * NEL;             // WqT/WkT/WvT/WoT contiguous
  ushort_t* WkT = WqT + (size_t)HID * HID;
  ushort_t* WvT = WkT + (size_t)HID * HID;
  ushort_t* WoT = WvT + (size_t)HID * HID;
  float* biasF  = (float*)(WoT + (size_t)HID * HID);   // q,k,v,o contiguous
  float* mbias  = biasF + 4 * HID;                     // BATCH*SEQ floats
  ushort_t* Cp2 = (ushort_t*)(mbias + (size_t)BATCH * SEQ);  // probe scratch, 8MB

  prep_all<<<296, 256, 0, stream>>>(Wq, Wk, Wv, Wo, WqT, WkT, WvT, WoT,
                                    bq, bk, bv, bo, biasF, mask, mbias,
                                    (const unsigned int*)query);

  gemm_qkv3<<<dim3(MTOT / 32, 1, 3), 256, 0, stream>>>(
      query, keys, values, WqT, biasF, Qp);

  // flashB: the real attention
  flash_attn<<<dim3(SEQ / 128, NH, BATCH), 512, 0, stream>>>(Qp, Kp, Vp, mbias, Cp);

  gemm_out2<<<dim3(MTOT / 64, HID / 128), 256, 0, stream>>>(
      Cp, WoT, biasF + 3 * HID, d_out, (const unsigned int*)query);

  // flashC: TIMESTAMP PROBE (this round only). Re-runs flash on the same valid
  // inputs into scratch Cp2 (never read; output unchanged). Both flash dispatches
  // land in rocprof top-5 with Start/End timestamps:
  //   Start(flashC) - End(flashB) = gap + gemm_out2 + gap   (first direct GEMM timing)
  flash_attn<<<dim3(SEQ / 128, NH, BATCH), 512, 0, stream>>>(Qp, Kp, Vp, mbias, Cp2);
}

// Round 10
// 221.612 us; speedup vs baseline: 1.3100x; 1.3100x over previous
//
#include <hip/hip_runtime.h>

#define HID 512
#define NH 8
#define HD 64
#define BATCH 4
#define SEQ 2048
#define MTOT (BATCH * SEQ)   // 8192

typedef unsigned short ushort_t;
typedef __bf16 bf16x8 __attribute__((ext_vector_type(8)));
typedef unsigned short ushort8v __attribute__((ext_vector_type(8)));
typedef unsigned short ushort4v __attribute__((ext_vector_type(4)));
typedef float floatx4 __attribute__((ext_vector_type(4)));
typedef unsigned int uintx4 __attribute__((ext_vector_type(4)));

static __device__ __forceinline__ unsigned short f2bf(float f) {
  __bf16 b = (__bf16)f;                    // hw v_cvt_pk_bf16_f32 (RNE)
  return __builtin_bit_cast(unsigned short, b);
}
static __device__ __forceinline__ float bf2f(unsigned short s) {
  union { unsigned int u; float f; } c; c.u = ((unsigned int)s) << 16;
  return c.f;
}
static __device__ __forceinline__ bf16x8 asbf(ushort8v v) {
  return __builtin_bit_cast(bf16x8, v);
}
static __device__ __forceinline__ float max3f(float a, float b, float c) {
  return fmaxf(fmaxf(a, b), c);            // v_max3_f32
}
static __device__ __forceinline__ float fexp2(float x) {
  return __builtin_amdgcn_exp2f(x);        // raw v_exp_f32
}
// async global->LDS, 16B/lane, linear dest (wave-uniform base + lane*16)
static __device__ __forceinline__ void gl_lds16(const ushort_t* g, ushort_t* l) {
  __builtin_amdgcn_global_load_lds(
      (const __attribute__((address_space(1))) void*)g,
      (__attribute__((address_space(3))) void*)l, 16, 0, 0);
}

// ---------- inline dtype detection (proven round 8) ----------
static __device__ __forceinline__ int detect_bf(const unsigned int* __restrict__ q) {
  int lane = threadIdx.x & 63;
  int hits = 0;
#pragma unroll
  for (int i = 0; i < 4; ++i) {
    unsigned e = (q[lane * 4 + i] >> 7) & 0xff;
    hits += (e >= 110 && e <= 136) ? 1 : 0;
  }
#pragma unroll
  for (int s = 1; s < 64; s <<= 1) hits += __shfl_xor(hits, s);
  return hits >= 128 ? 1 : 0;
}

// 0.125 (1/sqrt(64)) * log2(e): softmax in exp2 domain.
#define SC_LOG2E 0.18033688011112042f

// ---------- fused prep (proven round 8 verbatim) ----------
__global__ __launch_bounds__(256) void prep_all(
    const void* __restrict__ W0, const void* __restrict__ W1,
    const void* __restrict__ W2, const void* __restrict__ W3,
    ushort_t* __restrict__ T0, ushort_t* __restrict__ T1,
    ushort_t* __restrict__ T2, ushort_t* __restrict__ T3,
    const void* __restrict__ B0, const void* __restrict__ B1,
    const void* __restrict__ B2, const void* __restrict__ B3,
    float* __restrict__ biasF, const int* __restrict__ mask,
    float* __restrict__ mb, const unsigned int* __restrict__ qd) {
  const int bx = blockIdx.x;
  const int isbf = detect_bf(qd);
  if (bx < 256) {
    const int sel = bx >> 6, t = bx & 63;
    const void* W; ushort_t* T;
    switch (sel) {
      case 0: W = W0; T = T0; break;
      case 1: W = W1; T = T1; break;
      case 2: W = W2; T = T2; break;
      default: W = W3; T = T3; break;
    }
    __shared__ ushort_t Ts[64 * 72];
    const int tid = threadIdx.x;
    const int kt = (t >> 3) * 64;
    const int nt = (t & 7) * 64;
    const int r = tid >> 2;             // 0..63
    const int c = (tid & 3) * 16;       // 0,16,32,48

    ushort8v v0, v1;
    if (isbf) {
      const ushort_t* p = (const ushort_t*)W + (long)(kt + r) * HID + nt + c;
      v0 = *(const ushort8v*)(p);
      v1 = *(const ushort8v*)(p + 8);
    } else {
      const float* p = (const float*)W + (long)(kt + r) * HID + nt + c;
      floatx4 f0 = *(const floatx4*)(p);
      floatx4 f1 = *(const floatx4*)(p + 4);
      floatx4 f2 = *(const floatx4*)(p + 8);
      floatx4 f3 = *(const floatx4*)(p + 12);
#pragma unroll
      for (int i = 0; i < 4; ++i) {
        v0[i] = f2bf(f0[i]); v0[4 + i] = f2bf(f1[i]);
        v1[i] = f2bf(f2[i]); v1[4 + i] = f2bf(f3[i]);
      }
    }
    *(ushort8v*)(&Ts[r * 72 + c])     = v0;
    *(ushort8v*)(&Ts[r * 72 + c + 8]) = v1;
    __syncthreads();
    ushort8v o0, o1;
#pragma unroll
    for (int j = 0; j < 8; ++j) o0[j] = Ts[(c + j) * 72 + r];
#pragma unroll
    for (int j = 0; j < 8; ++j) o1[j] = Ts[(c + 8 + j) * 72 + r];
    ushort_t* q = T + (long)(nt + r) * HID + kt + c;
    *(ushort8v*)(q)     = o0;
    *(ushort8v*)(q + 8) = o1;
  } else if (bx < 264) {
    int i = (bx - 256) * 256 + threadIdx.x;
    int t = i >> 9, j = i & 511;
    const void* B = (t == 0) ? B0 : (t == 1) ? B1 : (t == 2) ? B2 : B3;
    biasF[i] = isbf ? bf2f(((const ushort_t*)B)[j]) : ((const float*)B)[j];
  } else {
    int i = (bx - 264) * 256 + threadIdx.x;
    mb[i] = mask[i] ? 0.f : -1e9f;
  }
}

// ---------- QKV GEMM v5: BM=64, BN=256, BK=64, dbuf write-late ----------
// r7's proven schedule (issue-early staging, compute, ds_write-late, ONE
// barrier/iter) at 4x the MFMA per step (32/wave/step): the compute phase is
// now long enough to hide staging latency. A (f32 or bf16 X) reg-staged with
// fused convert; B (Wt bf16) via gl_lds. Swizzle math verbatim from r8.
// LDS 80KB -> 2 blocks/CU. Grid 768 = 3z x 128m x 2n, XCD-swizzled.
__global__ __launch_bounds__(256) void gemm_qkv5(
    const void* __restrict__ X0, const void* __restrict__ X1, const void* __restrict__ X2,
    const ushort_t* __restrict__ WtBase, const float* __restrict__ biasBase,
    ushort_t* __restrict__ YBase) {
  const int isbf = detect_bf((const unsigned int*)X0);
  int lin = blockIdx.x;                             // 0..767
  int swz = (lin & 7) * 96 + (lin >> 3);            // bijective: 768 = 8*96
  const int z = swz >> 8;                           // 0..2
  const int rem = swz & 255;                        // 128m x 2n
  const int m0 = (rem >> 1) * 64;
  const int n0 = (rem & 1) * 256;
  const void* X = (z == 0) ? X0 : (z == 1) ? X1 : X2;
  const ushort_t* Wt = WtBase + (size_t)z * HID * HID;
  const float* biasF = biasBase + (size_t)z * HID;
  ushort_t* Y = YBase + (size_t)z * MTOT * HID;

  const int tid = threadIdx.x;
  const int wid = tid >> 6, lane = tid & 63;
  const int id = lane & 15, quad = lane >> 4;
  const int wm = wid >> 1, wn = wid & 1;

  __shared__ ushort_t As[2][64 * 64];    // 8KB x2
  __shared__ ushort_t Bs[2][256 * 64];   // 32KB x2  (total 80KB)

  // A reg-stage: 2 slots/thread; slot s -> idx=tid*2+s, row=idx>>3, cb=idx&7
  // B gl_lds: 8-row stripes, 8/wave; lane -> rowoff lane>>3, colblk lane&7
  const int b_ro = lane >> 3;
  const int b_cb = lane & 7;

  floatx4 acc[2][8];
#pragma unroll
  for (int i = 0; i < 2; ++i)
#pragma unroll
    for (int j = 0; j < 8; ++j) acc[i][j] = (floatx4){0.f, 0.f, 0.f, 0.f};

  ushort8v aR[2];
  // ---- prologue: stage tile 0 into buf 0 ----
#pragma unroll
  for (int s = 0; s < 2; ++s) {
    int idx = tid * 2 + s, row = idx >> 3, cb = idx & 7;
    if (isbf) {
      aR[s] = *(const ushort8v*)((const ushort_t*)X + (long)(m0 + row) * HID + cb * 8);
    } else {
      const float* p = (const float*)X + (long)(m0 + row) * HID + cb * 8;
      floatx4 f0 = *(const floatx4*)(p);
      floatx4 f1 = *(const floatx4*)(p + 4);
#pragma unroll
      for (int i = 0; i < 4; ++i) { aR[s][i] = f2bf(f0[i]); aR[s][4 + i] = f2bf(f1[i]); }
    }
  }
#pragma unroll
  for (int i = 0; i < 8; ++i) {
    int j = wid * 8 + i;                 // stripe 0..31
    gl_lds16(Wt + (long)(n0 + j * 8 + b_ro) * HID + ((b_cb ^ b_ro) << 3),
             &Bs[0][(j * 8) * 64]);
  }
#pragma unroll
  for (int s = 0; s < 2; ++s) {
    int idx = tid * 2 + s, row = idx >> 3, cb = idx & 7;
    *(ushort8v*)(&As[0][row * 64 + ((cb ^ (row & 7)) << 3)]) = aR[s];
  }
  __syncthreads();

  int cur = 0;
  for (int t = 0; t < 8; ++t) {
    const bool more = (t + 1 < 8);
    if (more) {
      const int k1 = (t + 1) * 64;
#pragma unroll
      for (int s = 0; s < 2; ++s) {
        int idx = tid * 2 + s, row = idx >> 3, cb = idx & 7;
        if (isbf) {
          aR[s] = *(const ushort8v*)((const ushort_t*)X + (long)(m0 + row) * HID + k1 + cb * 8);
        } else {
          const float* p = (const float*)X + (long)(m0 + row) * HID + k1 + cb * 8;
          floatx4 f0 = *(const floatx4*)(p);
          floatx4 f1 = *(const floatx4*)(p + 4);
#pragma unroll
          for (int i = 0; i < 4; ++i) { aR[s][i] = f2bf(f0[i]); aR[s][4 + i] = f2bf(f1[i]); }
        }
      }
#pragma unroll
      for (int i = 0; i < 8; ++i) {
        int j = wid * 8 + i;
        gl_lds16(Wt + (long)(n0 + j * 8 + b_ro) * HID + k1 + ((b_cb ^ b_ro) << 3),
                 &Bs[cur ^ 1][(j * 8) * 64]);
      }
    }
    // ---- compute: 32 MFMA/wave from buf[cur] ----
#pragma unroll
    for (int kk = 0; kk < 64; kk += 32) {
      ushort8v af[2], bfv[8];
      const int cb = (kk >> 3) + quad;
      const int px = (cb ^ (id & 7)) << 3;
#pragma unroll
      for (int ms = 0; ms < 2; ++ms)
        af[ms] = *(const ushort8v*)(&As[cur][(wm * 32 + ms * 16 + id) * 64 + px]);
#pragma unroll
      for (int ns = 0; ns < 8; ++ns)
        bfv[ns] = *(const ushort8v*)(&Bs[cur][(wn * 128 + ns * 16 + id) * 64 + px]);
#pragma unroll
      for (int ms = 0; ms < 2; ++ms)
#pragma unroll
        for (int ns = 0; ns < 8; ++ns)
          acc[ms][ns] = __builtin_amdgcn_mfma_f32_16x16x32_bf16(asbf(af[ms]), asbf(bfv[ns]), acc[ms][ns], 0, 0, 0);
    }
    if (more) {                          // write-late: A-load latency hidden
#pragma unroll
      for (int s = 0; s < 2; ++s) {
        int idx = tid * 2 + s, row = idx >> 3, cb = idx & 7;
        *(ushort8v*)(&As[cur ^ 1][row * 64 + ((cb ^ (row & 7)) << 3)]) = aR[s];
      }
    }
    __syncthreads();
    cur ^= 1;
  }
#pragma unroll
  for (int ns = 0; ns < 8; ++ns) {
    int col = n0 + wn * 128 + ns * 16 + id;
    float bv = biasF[col];
#pragma unroll
    for (int ms = 0; ms < 2; ++ms) {
      int row0 = m0 + wm * 32 + ms * 16 + quad * 4;
#pragma unroll
      for (int r = 0; r < 4; ++r)
        Y[(long)(row0 + r) * HID + col] = f2bf(acc[ms][ns][r] + bv);
    }
  }
}

// ---------- out-proj GEMM v5: BM=64, BN=128, BK=64, dbuf, both gl_lds ----------
// Same schedule; X (Cp) always bf16 so both operands via gl_lds.
// LDS 48KB -> 3 blocks/CU. Grid 512 = 128m x 4n, XCD-swizzled.
__global__ __launch_bounds__(256) void gemm_out5(
    const ushort_t* __restrict__ X, const ushort_t* __restrict__ Wt,
    const float* __restrict__ biasF, void* __restrict__ out,
    const unsigned int* __restrict__ qd) {
  const int isbf = detect_bf(qd);
  int lin = blockIdx.x;                             // 0..511
  int swz = (lin & 7) * 64 + (lin >> 3);            // bijective: 512 = 8*64
  const int m0 = (swz >> 2) * 64;
  const int n0 = (swz & 3) * 128;

  const int tid = threadIdx.x;
  const int wid = tid >> 6, lane = tid & 63;
  const int id = lane & 15, quad = lane >> 4;
  const int wm = wid >> 1, wn = wid & 1;

  __shared__ ushort_t As[2][64 * 64];    // 8KB x2
  __shared__ ushort_t Bs[2][128 * 64];   // 16KB x2  (total 48KB)

  const int b_ro = lane >> 3;
  const int b_cb = lane & 7;

  floatx4 acc[2][4];
#pragma unroll
  for (int i = 0; i < 2; ++i)
#pragma unroll
    for (int j = 0; j < 4; ++j) acc[i][j] = (floatx4){0.f, 0.f, 0.f, 0.f};

  // ---- prologue: stage tile 0 into buf 0 ----
#pragma unroll
  for (int i = 0; i < 2; ++i) {
    int j = wid * 2 + i;                 // A stripe 0..7
    gl_lds16(X + (long)(m0 + j * 8 + b_ro) * HID + ((b_cb ^ b_ro) << 3),
             &As[0][(j * 8) * 64]);
  }
#pragma unroll
  for (int i = 0; i < 4; ++i) {
    int j = wid * 4 + i;                 // B stripe 0..15
    gl_lds16(Wt + (long)(n0 + j * 8 + b_ro) * HID + ((b_cb ^ b_ro) << 3),
             &Bs[0][(j * 8) * 64]);
  }
  __syncthreads();

  int cur = 0;
  for (int t = 0; t < 8; ++t) {
    const bool more = (t + 1 < 8);
    if (more) {
      const int k1 = (t + 1) * 64;
#pragma unroll
      for (int i = 0; i < 2; ++i) {
        int j = wid * 2 + i;
        gl_lds16(X + (long)(m0 + j * 8 + b_ro) * HID + k1 + ((b_cb ^ b_ro) << 3),
                 &As[cur ^ 1][(j * 8) * 64]);
      }
#pragma unroll
      for (int i = 0; i < 4; ++i) {
        int j = wid * 4 + i;
        gl_lds16(Wt + (long)(n0 + j * 8 + b_ro) * HID + k1 + ((b_cb ^ b_ro) << 3),
                 &Bs[cur ^ 1][(j * 8) * 64]);
      }
    }
#pragma unroll
    for (int kk = 0; kk < 64; kk += 32) {
      ushort8v af[2], bfv[4];
      const int cb = (kk >> 3) + quad;
      const int px = (cb ^ (id & 7)) << 3;
#pragma unroll
      for (int ms = 0; ms < 2; ++ms)
        af[ms] = *(const ushort8v*)(&As[cur][(wm * 32 + ms * 16 + id) * 64 + px]);
#pragma unroll
      for (int ns = 0; ns < 4; ++ns)
        bfv[ns] = *(const ushort8v*)(&Bs[cur][(wn * 64 + ns * 16 + id) * 64 + px]);
#pragma unroll
      for (int ms = 0; ms < 2; ++ms)
#pragma unroll
        for (int ns = 0; ns < 4; ++ns)
          acc[ms][ns] = __builtin_amdgcn_mfma_f32_16x16x32_bf16(asbf(af[ms]), asbf(bfv[ns]), acc[ms][ns], 0, 0, 0);
    }
    __syncthreads();
    cur ^= 1;
  }
#pragma unroll
  for (int ns = 0; ns < 4; ++ns) {
    int col = n0 + wn * 64 + ns * 16 + id;
    float bv = biasF[col];
#pragma unroll
    for (int ms = 0; ms < 2; ++ms) {
      int row0 = m0 + wm * 32 + ms * 16 + quad * 4;
      if (isbf) {
        ushort_t* o = (ushort_t*)out;
#pragma unroll
        for (int r = 0; r < 4; ++r) o[(long)(row0 + r) * HID + col] = f2bf(acc[ms][ns][r] + bv);
      } else {
        float* o = (float*)out;
#pragma unroll
        for (int r = 0; r < 4; ++r) o[(long)(row0 + r) * HID + col] = acc[ms][ns][r] + bv;
      }
    }
  }
}

// ---------- flash attention — ROUND-3 VERSION VERBATIM (proven ~79-81us) ----------
__global__ __launch_bounds__(512) void flash_attn(
    const ushort_t* __restrict__ Q, const ushort_t* __restrict__ K,
    const ushort_t* __restrict__ V, const float* __restrict__ mb,
    ushort_t* __restrict__ ctx) {
  int lin = blockIdx.x + 16 * blockIdx.y + 128 * blockIdx.z;   // 0..511
  int swz = (lin & 7) * 64 + (lin >> 3);                       // bijective
  const int qblk = swz & 15, h = (swz >> 4) & 7, b = swz >> 7;
  const int tid = threadIdx.x;
  const int wid = tid >> 6, lane = tid & 63;
  const int id = lane & 15, quad = lane >> 4;

  __shared__ ushort_t Kt[64 * 72];       // [key][d] stride 72
  __shared__ ushort_t Vt[64 * 72];       // [d][key] stride 72 (transposed)
  __shared__ ushort_t Pl[8][16 * 72];    // per-wave P as [q][key] stride 72

  const ushort_t* Qb = Q + (long)(b * SEQ + qblk * 128 + wid * 16) * HID + h * HD;
  const ushort_t* Kb = K + (long)(b * SEQ) * HID + h * HD;
  const ushort_t* Vb = V + (long)(b * SEQ) * HID + h * HD;
  const float* mrow = mb + b * SEQ;

  ushort8v qf[2];
#pragma unroll
  for (int kh = 0; kh < 2; ++kh)
    qf[kh] = *(const ushort8v*)(Qb + id * HID + kh * 32 + quad * 8);

  floatx4 o[4];
  float m_i = -1e30f, l_i = 0.f;
#pragma unroll
  for (int dg = 0; dg < 4; ++dg) o[dg] = (floatx4){0, 0, 0, 0};

  const bool kstager = (tid < 256);
  const int t2 = tid & 255;
  const int skey = t2 >> 2;              // K: rows 0..63
  const int sdc  = (t2 & 3) * 16;        // K: cols 0,16,32,48
  const int vkp  = (t2 & 31) * 2;        // V: key pair 0..62
  const int vdc  = (t2 >> 5) * 8;        // V: d col 0..56

  ushort8v r0, r1;
  if (kstager) {
    const ushort_t* kpp = Kb + (long)skey * HID + sdc;
    r0 = *(const ushort8v*)(kpp);
    r1 = *(const ushort8v*)(kpp + 8);
  } else {
    const ushort_t* vp0 = Vb + (long)vkp * HID + vdc;
    r0 = *(const ushort8v*)(vp0);
    r1 = *(const ushort8v*)(vp0 + HID);
  }

  for (int kb = 0; kb < SEQ / 64; ++kb) {
    if (kstager) {
      *(ushort8v*)(&Kt[skey * 72 + sdc])     = r0;
      *(ushort8v*)(&Kt[skey * 72 + sdc + 8]) = r1;
    } else {
      uintx4 a = __builtin_bit_cast(uintx4, r0);
      uintx4 bq = __builtin_bit_cast(uintx4, r1);
#pragma unroll
      for (int j = 0; j < 4; ++j) {
        unsigned int d0 = __builtin_amdgcn_perm(bq[j], a[j], 0x05040100u);
        unsigned int d1 = __builtin_amdgcn_perm(bq[j], a[j], 0x07060302u);
        *(unsigned int*)(&Vt[(vdc + 2 * j) * 72 + vkp])     = d0;
        *(unsigned int*)(&Vt[(vdc + 2 * j + 1) * 72 + vkp]) = d1;
      }
    }
    __syncthreads();

    if (kb + 1 < SEQ / 64) {
      if (kstager) {
        const ushort_t* kpp = Kb + (long)((kb + 1) * 64 + skey) * HID + sdc;
        r0 = *(const ushort8v*)(kpp);
        r1 = *(const ushort8v*)(kpp + 8);
      } else {
        const ushort_t* vp0 = Vb + (long)((kb + 1) * 64 + vkp) * HID + vdc;
        r0 = *(const ushort8v*)(vp0);
        r1 = *(const ushort8v*)(vp0 + HID);
      }
    }

    floatx4 st[4];
    __builtin_amdgcn_s_setprio(1);
#pragma unroll
    for (int ks = 0; ks < 4; ++ks) {
      ushort8v kf0 = *(const ushort8v*)(&Kt[(ks * 16 + id) * 72 + quad * 8]);
      ushort8v kf1 = *(const ushort8v*)(&Kt[(ks * 16 + id) * 72 + 32 + quad * 8]);
      floatx4 a = (floatx4){0, 0, 0, 0};
      a = __builtin_amdgcn_mfma_f32_16x16x32_bf16(asbf(kf0), asbf(qf[0]), a, 0, 0, 0);
      a = __builtin_amdgcn_mfma_f32_16x16x32_bf16(asbf(kf1), asbf(qf[1]), a, 0, 0, 0);
      st[ks] = a;
    }
    __builtin_amdgcn_s_setprio(0);
#pragma unroll
    for (int ks = 0; ks < 4; ++ks) {
      floatx4 mbv = *(const floatx4*)(mrow + kb * 64 + ks * 16 + quad * 4);
#pragma unroll
      for (int r = 0; r < 4; ++r)
        st[ks][r] = fmaf(st[ks][r], SC_LOG2E, mbv[r]);
    }
    {
      float t0 = max3f(st[0][0], st[0][1], st[0][2]);
      float t1 = max3f(st[0][3], st[1][0], st[1][1]);
      float t2m = max3f(st[1][2], st[1][3], st[2][0]);
      float t3 = max3f(st[2][1], st[2][2], st[2][3]);
      float t4 = max3f(st[3][0], st[3][1], st[3][2]);
      float mx = max3f(t0, t1, st[3][3]);
      float mz = max3f(t2m, t3, t4);
      mx = fmaxf(mx, mz);
      mx = fmaxf(mx, __shfl_xor(mx, 16));
      mx = fmaxf(mx, __shfl_xor(mx, 32));
      if (!__all(mx - m_i <= 8.f)) {
        float mnew = fmaxf(m_i, mx);
        float alpha = fexp2(m_i - mnew);
        m_i = mnew;
        l_i *= alpha;
#pragma unroll
        for (int dg = 0; dg < 4; ++dg) o[dg] *= alpha;
      }
      float mcur = m_i;
      floatx4 rsv = (floatx4){0.f, 0.f, 0.f, 0.f};
#pragma unroll
      for (int ks = 0; ks < 4; ++ks) {
        ushort4v pk;
#pragma unroll
        for (int r = 0; r < 4; ++r) {
          float p = fexp2(st[ks][r] - mcur);
          rsv[r] += p;
          pk[r] = f2bf(p);
        }
        *(ushort4v*)(&Pl[wid][id * 72 + ks * 16 + quad * 4]) = pk;
      }
      float rs = (rsv[0] + rsv[1]) + (rsv[2] + rsv[3]);
      rs += __shfl_xor(rs, 16);
      rs += __shfl_xor(rs, 32);
      l_i += rs;
    }

    __builtin_amdgcn_s_setprio(1);
#pragma unroll
    for (int kc = 0; kc < 2; ++kc) {
      ushort8v pf = *(const ushort8v*)(&Pl[wid][id * 72 + kc * 32 + quad * 8]);
#pragma unroll
      for (int dg = 0; dg < 4; ++dg) {
        ushort8v vf = *(const ushort8v*)(&Vt[(dg * 16 + id) * 72 + kc * 32 + quad * 8]);
        o[dg] = __builtin_amdgcn_mfma_f32_16x16x32_bf16(asbf(vf), asbf(pf), o[dg], 0, 0, 0);
      }
    }
    __builtin_amdgcn_s_setprio(0);
    __syncthreads();
  }

  {
    float inv = 1.0f / l_i;
    long qrow = (long)(b * SEQ + qblk * 128 + wid * 16 + id);
#pragma unroll
    for (int dg = 0; dg < 4; ++dg) {
      ushort4v pk;
#pragma unroll
      for (int r = 0; r < 4; ++r) pk[r] = f2bf(o[dg][r] * inv);
      *(ushort4v*)(&ctx[qrow * HID + h * HD + dg * 16 + quad * 4]) = pk;
    }
  }
}

extern "C" void kernel_launch(void* const* d_in, const int* in_sizes, int n_in,
                              void* d_out, int out_size, void* d_ws, size_t ws_size,
                              hipStream_t stream) {
  const void* values = d_in[0];
  const void* keys   = d_in[1];
  const void* query  = d_in[2];
  const int*  mask   = (const int*)d_in[3];
  const void* Wq = d_in[4];  const void* bq = d_in[5];
  const void* Wk = d_in[6];  const void* bk = d_in[7];
  const void* Wv = d_in[8];  const void* bv = d_in[9];
  const void* Wo = d_in[10]; const void* bo = d_in[11];

  ushort_t* ws = (ushort_t*)d_ws;
  const size_t NEL = (size_t)MTOT * HID;
  ushort_t* Qp  = ws;                       // Qp/Kp/Vp contiguous
  ushort_t* Kp  = ws + NEL;
  ushort_t* Vp  = ws + 2 * NEL;
  ushort_t* Cp  = ws + 3 * NEL;
  ushort_t* WqT = ws + 4 * NEL;             // WqT/WkT/WvT/WoT contiguous
  ushort_t* WkT = WqT + (size_t)HID * HID;
  ushort_t* WvT = WkT + (size_t)HID * HID;
  ushort_t* WoT = WvT + (size_t)HID * HID;
  float* biasF  = (float*)(WoT + (size_t)HID * HID);   // q,k,v,o contiguous
  float* mbias  = biasF + 4 * HID;                     // BATCH*SEQ floats

  prep_all<<<296, 256, 0, stream>>>(Wq, Wk, Wv, Wo, WqT, WkT, WvT, WoT,
                                    bq, bk, bv, bo, biasF, mask, mbias,
                                    (const unsigned int*)query);

  // QKV: 64x256 tile dbuf (32 MFMA/wave/step); 768 blocks XCD-swizzled
  gemm_qkv5<<<768, 256, 0, stream>>>(query, keys, values, WqT, biasF, Qp);

  flash_attn<<<dim3(SEQ / 128, NH, BATCH), 512, 0, stream>>>(Qp, Kp, Vp, mbias, Cp);

  // out-proj: 64x128 tile dbuf; 512 blocks XCD-swizzled
  gemm_out5<<<512, 256, 0, stream>>>(Cp, WoT, biasF + 3 * HID, d_out,
                                     (const unsigned int*)query);
}